// Round 12
// baseline (110.791 us; speedup 1.0000x reference)
//
#include <hip/hip_runtime.h>
#include <hip/hip_bf16.h>

#define T_LEN 8192
#define H_DIM 512
#define P_DIM 512
#define CS 16
#define NB (T_LEN / CS)   // 512 chunks

typedef __attribute__((ext_vector_type(8))) __bf16 bf16x8;
typedef __attribute__((ext_vector_type(4))) float f32x4;

__device__ __forceinline__ unsigned short f2bf(float f) {
    __bf16 h = (__bf16)f;
    return __builtin_bit_cast(unsigned short, h);
}
__device__ __forceinline__ float bf2f(unsigned short u) {
    unsigned v = ((unsigned)u) << 16;
    return __builtin_bit_cast(float, v);
}

__device__ __forceinline__ void gload_lds16(void* g, void* l) {
    __builtin_amdgcn_global_load_lds(
        (__attribute__((address_space(1))) unsigned*)g,
        (__attribute__((address_space(3))) unsigned*)l, 16, 0, 0);
}

// lambda_bar(p) in f64 — formula identical everywhere it is inlined.
__device__ __forceinline__ void lbar_of(const float* lam_re, const float* lam_im,
                                        const float* log_step, int p,
                                        double& lbr, double& lbi) {
    double lr = fmin((double)lam_re[p], -1e-4);
    double li = (double)lam_im[p];
    double step = exp((double)log_step[p]);          // STEP_RESCALE = 1
    double er = exp(lr * step);
    double ang = li * step;
    lbr = er * cos(ang);
    lbi = er * sin(ang);
}

// ---------------------------------------------------------------------------
// prep: 4096 blocks: x (f32) -> xhi/xlo bf16 split, float4 in / 8B out.
//       blocks < 1024 additionally fill Bt1 / Bt2 as bf16 hi/lo; coef inline.
// ---------------------------------------------------------------------------
__global__ __launch_bounds__(256) void prep_kernel(
    const float* __restrict__ x,
    const float* __restrict__ b, const float* __restrict__ c,
    const float* __restrict__ lam_re, const float* __restrict__ lam_im,
    const float* __restrict__ log_step,
    unsigned short* __restrict__ xhi, unsigned short* __restrict__ xlo,
    unsigned short* __restrict__ Bt1hi, unsigned short* __restrict__ Bt1lo,
    unsigned short* __restrict__ Bt2hi, unsigned short* __restrict__ Bt2lo) {
    int idx = blockIdx.x * 256 + threadIdx.x;        // 0 .. T*H/4-1
    {
        float4 v = ((const float4*)x)[idx];
        ushort4 h, l;
        h.x = f2bf(v.x); l.x = f2bf(v.x - bf2f(h.x));
        h.y = f2bf(v.y); l.y = f2bf(v.y - bf2f(h.y));
        h.z = f2bf(v.z); l.z = f2bf(v.z - bf2f(h.z));
        h.w = f2bf(v.w); l.w = f2bf(v.w - bf2f(h.w));
        ((ushort4*)xhi)[idx] = h;
        ((ushort4*)xlo)[idx] = l;
    }
    if (blockIdx.x < (P_DIM * H_DIM) / 256) {
        int idx2 = blockIdx.x * 256 + threadIdx.x;   // 0 .. 262143
        {   // Bt1: rows 2p,2p+1 (stride H_DIM), coalesced in h
            int p = idx2 >> 9, h = idx2 & 511;
            double lr = fmin((double)lam_re[p], -1e-4);
            double li = (double)lam_im[p];
            double step = exp((double)log_step[p]);
            double er = exp(lr * step);
            double ang = li * step;
            double lbr = er * cos(ang), lbi = er * sin(ang);
            double nr = lbr - 1.0, ni = lbi;
            double den = lr * lr + li * li;
            double cr = (nr * lr + ni * li) / den;
            double ci = (ni * lr - nr * li) / den;
            float2 bv = ((const float2*)b)[(size_t)p * H_DIM + h];
            float re = (float)(cr * (double)bv.x - ci * (double)bv.y);
            float im = (float)(cr * (double)bv.y + ci * (double)bv.x);
            unsigned short rh = f2bf(re), ih = f2bf(im);
            Bt1hi[(size_t)(2 * p) * H_DIM + h]     = rh;
            Bt1lo[(size_t)(2 * p) * H_DIM + h]     = f2bf(re - bf2f(rh));
            Bt1hi[(size_t)(2 * p + 1) * H_DIM + h] = ih;
            Bt1lo[(size_t)(2 * p + 1) * H_DIM + h] = f2bf(im - bf2f(ih));
        }
        {   // Bt2: row h (stride 2P), cols 2p,2p+1 -> ushort2, coalesced in p
            int h = idx2 >> 9, p = idx2 & 511;
            float2 cv = ((const float2*)c)[(size_t)h * P_DIM + p];
            float re = cv.x, im = -cv.y;
            ushort2 hi, lo;
            hi.x = f2bf(re); lo.x = f2bf(re - bf2f(hi.x));
            hi.y = f2bf(im); lo.y = f2bf(im - bf2f(hi.y));
            ((ushort2*)Bt2hi)[(size_t)h * P_DIM + p] = hi;
            ((ushort2*)Bt2lo)[(size_t)h * P_DIM + p] = lo;
        }
    }
}

// ---------------------------------------------------------------------------
// Split-bf16 MFMA GEMM, 8-wave variant: C = (Ahi+Alo) * (Bthi+Btlo)^T.
// 128x128 tile, BK=32, 512 thr = 8 waves (4M x 2N); wave tile 32x64,
// acc 2x4. Same LDS (64KB dbuf), same staging bytes/swizzles as 4-wave
// version — only the wave decomposition changes (2x waves/SIMD for TLP).
// MODE 0: write C as bf16 hi/lo split + fused scanA chunk summaries.
// MODE 1: write f32 C + D[col]*X[row][col].
// ---------------------------------------------------------------------------
template <int MODE>
__global__ __launch_bounds__(512, 4) void gemm_mfma_split(
    const unsigned short* __restrict__ Ahi, const unsigned short* __restrict__ Alo,
    int lda,
    const unsigned short* __restrict__ Bthi, const unsigned short* __restrict__ Btlo,
    int ldb,
    void* __restrict__ Cout0, void* __restrict__ Cout1, int ldc, int K,
    const float* __restrict__ Dvec, const float* __restrict__ X,
    const float* __restrict__ mask,
    const float* __restrict__ lam_re, const float* __restrict__ lam_im,
    const float* __restrict__ log_step,
    double* __restrict__ cA, double* __restrict__ cS, float* __restrict__ cC) {
    __shared__ __align__(16) unsigned short lds[2][4][128 * 32];
    const int tid = threadIdx.x;
    const int lane = tid & 63, wid = tid >> 6;       // 8 waves
    const int wm = wid >> 1, wn = wid & 1;           // 4M x 2N

    // XCD swizzle (bijective: gy % 8 == 0)
    const int id = blockIdx.y * gridDim.x + blockIdx.x;
    const int nx = gridDim.x, rpx = gridDim.y >> 3;
    const int xcd = id & 7, j = id >> 3;
    const int by = xcd * rpx + j / nx;
    const int bx = j % nx;
    const int bm = by * 128, bn = bx * 128;

    // staging: tile (wid>>1) of {Ahi,Alo,Bthi,Btlo}; each wave does 4 of the
    // tile's 8 1KB segments: rg = (wid&1)*4 + s.
    const unsigned short* ssrc;
    int srow0, sld;
    {
        int tile = wid >> 1;
        if (tile == 0)      { ssrc = Ahi;  srow0 = bm; sld = lda; }
        else if (tile == 1) { ssrc = Alo;  srow0 = bm; sld = lda; }
        else if (tile == 2) { ssrc = Bthi; srow0 = bn; sld = ldb; }
        else                { ssrc = Btlo; srow0 = bn; sld = ldb; }
    }

    f32x4 acc[2][4];
#pragma unroll
    for (int i = 0; i < 2; ++i)
#pragma unroll
        for (int j2 = 0; j2 < 4; ++j2) acc[i][j2] = (f32x4)(0.0f);

    auto stage = [&](int buf, int k0) {
        unsigned short* base = &lds[buf][wid >> 1][0];
#pragma unroll
        for (int s = 0; s < 4; ++s) {
            int rg = ((wid & 1) << 2) + s;
            int r = rg * 16 + (lane >> 2);
            int cg = (lane & 3) ^ ((r >> 1) & 3);
            void* g = (void*)((const char*)(ssrc + (size_t)(srow0 + r) * sld + k0)
                              + cg * 16);
            gload_lds16(g, (void*)((char*)base + rg * 1024));
        }
    };

    stage(0, 0);
    __syncthreads();   // drains vmcnt

    const int nk = K / 32;
    for (int t = 0; t < nk; ++t) {
        int cur = t & 1;
        if (t + 1 < nk) stage(cur ^ 1, (t + 1) * 32);

        bf16x8 ah[2], al[2], bh[4], bl[4];
#pragma unroll
        for (int i = 0; i < 2; ++i) {
            int rA = wm * 32 + i * 16 + (lane & 15);
            int byA = rA * 64 + ((((lane >> 4)) ^ ((rA >> 1) & 3)) << 4);
            ah[i] = *(const bf16x8*)((const char*)&lds[cur][0][0] + byA);
            al[i] = *(const bf16x8*)((const char*)&lds[cur][1][0] + byA);
        }
#pragma unroll
        for (int j2 = 0; j2 < 4; ++j2) {
            int rB = wn * 64 + j2 * 16 + (lane & 15);
            int byB = rB * 64 + ((((lane >> 4)) ^ ((rB >> 1) & 3)) << 4);
            bh[j2] = *(const bf16x8*)((const char*)&lds[cur][2][0] + byB);
            bl[j2] = *(const bf16x8*)((const char*)&lds[cur][3][0] + byB);
        }
#pragma unroll
        for (int i = 0; i < 2; ++i)
#pragma unroll
            for (int j2 = 0; j2 < 4; ++j2) {
                acc[i][j2] = __builtin_amdgcn_mfma_f32_16x16x32_bf16(
                    ah[i], bh[j2], acc[i][j2], 0, 0, 0);
                acc[i][j2] = __builtin_amdgcn_mfma_f32_16x16x32_bf16(
                    ah[i], bl[j2], acc[i][j2], 0, 0, 0);
                acc[i][j2] = __builtin_amdgcn_mfma_f32_16x16x32_bf16(
                    al[i], bh[j2], acc[i][j2], 0, 0, 0);
            }
        __syncthreads();
    }

    // epilogue. C/D map (verified m89/m91): col = lane&15, row = 4*(lane>>4)+reg
#pragma unroll
    for (int i = 0; i < 2; ++i)
#pragma unroll
        for (int j2 = 0; j2 < 4; ++j2) {
            int col = bn + wn * 64 + j2 * 16 + (lane & 15);
#pragma unroll
            for (int r = 0; r < 4; ++r) {
                int row = bm + wm * 32 + i * 16 + (lane >> 4) * 4 + r;
                float v = acc[i][j2][r];
                if (MODE == 0) {
                    unsigned short h = f2bf(v);
                    unsigned short lo = f2bf(v - bf2f(h));
                    ((unsigned short*)Cout0)[(size_t)row * ldc + col] = h;
                    ((unsigned short*)Cout1)[(size_t)row * ldc + col] = lo;
                } else {
                    v += Dvec[col] * X[(size_t)row * ldc + col];
                    ((float*)Cout0)[(size_t)row * ldc + col] = v;
                }
            }
        }

    // ---- fused scanA (MODE 0 only): per-chunk fold of this block's tile ----
    if constexpr (MODE == 0) {
        float* fl = (float*)&lds[0][0][0];   // reuse staging LDS: [128][128] f32
        __syncthreads();                     // all epilogue reads of lds done
#pragma unroll
        for (int i = 0; i < 2; ++i)
#pragma unroll
            for (int j2 = 0; j2 < 4; ++j2) {
                int lcol = wn * 64 + j2 * 16 + (lane & 15);
#pragma unroll
                for (int r = 0; r < 4; ++r) {
                    int lrow = wm * 32 + i * 16 + (lane >> 4) * 4 + r;
                    fl[lrow * 128 + lcol] = acc[i][j2][r];
                }
            }
        __syncthreads();
        // 512 threads, 512 work items: q = tid&63 (local p), ck = tid>>6
        int q = tid & 63;
        int ck = tid >> 6;                   // local chunk 0..7
        int pg = (bn >> 1) + q;              // global p
        double lbr, lbi;
        lbar_of(lam_re, lam_im, log_step, pg, lbr, lbi);
        double Ar = 1., Ai = 0., Sr = 0., Si = 0.;
        float Cc = 0.f;
        for (int k = 0; k < CS; ++k) {
            int row = ck * CS + k;
            float m = mask[bm + row];
            double bxr = (double)fl[row * 128 + 2 * q];
            double bxi = (double)fl[row * 128 + 2 * q + 1];
            if (m != 0.f) {
                Ar = lbr; Ai = lbi; Sr = bxr; Si = bxi; Cc = 1.f;
            } else {
                double nAr = lbr * Ar - lbi * Ai;
                Ai = lbr * Ai + lbi * Ar; Ar = nAr;
                double nSr = lbr * Sr - lbi * Si + bxr;
                Si = lbr * Si + lbi * Sr + bxi; Sr = nSr;
            }
        }
        int cg = (bm / CS) + ck;             // global chunk
        cA[(size_t)cg * 1024 + 2 * pg]     = Ar;
        cA[(size_t)cg * 1024 + 2 * pg + 1] = Ai;
        cS[(size_t)cg * 1024 + 2 * pg]     = Sr;
        cS[(size_t)cg * 1024 + 2 * pg + 1] = Si;
        cC[(size_t)cg * P_DIM + pg] = Cc;
    }
}

// ---------------------------------------------------------------------------
// Scan phase B (f64, parallel, shuffle-based): one block per p (512 blocks),
// NB=512 threads (one per chunk) = 8 waves. In-wave Kogge-Stone via
// __shfl_up, serial scan of 8 wave totals, apply wave prefix + carry.
// ---------------------------------------------------------------------------
__global__ __launch_bounds__(NB) void scanB_kernel(
    const double* __restrict__ cA, const double* __restrict__ cS,
    const float* __restrict__ cC, const float* __restrict__ carry,
    double* __restrict__ prefix) {
    int p = blockIdx.x;      // 0..511
    int i = threadIdx.x;     // chunk 0..NB-1
    int lane = i & 63, w = i >> 6;
    __shared__ double tAr[8], tAi[8], tSr[8], tSi[8];
    __shared__ float  tC[8];
    __shared__ double eAr[8], eAi[8], eSr[8], eSi[8];
    __shared__ float  eC[8];

    double Ar = cA[(size_t)i * 1024 + 2 * p];
    double Ai = cA[(size_t)i * 1024 + 2 * p + 1];
    double Sr = cS[(size_t)i * 1024 + 2 * p];
    double Si = cS[(size_t)i * 1024 + 2 * p + 1];
    float  C  = cC[(size_t)i * P_DIM + p];

    // level 1: in-wave inclusive Kogge-Stone
#pragma unroll
    for (int d = 1; d < 64; d <<= 1) {
        double pAr = __shfl_up(Ar, d), pAi = __shfl_up(Ai, d);
        double pSr = __shfl_up(Sr, d), pSi = __shfl_up(Si, d);
        float  pC  = __shfl_up(C, d);
        if (lane >= d && C == 0.f) {
            double nAr = Ar * pAr - Ai * pAi;
            double nAi = Ar * pAi + Ai * pAr;
            double nSr = Ar * pSr - Ai * pSi + Sr;
            double nSi = Ar * pSi + Ai * pSr + Si;
            Ar = nAr; Ai = nAi; Sr = nSr; Si = nSi; C = pC;
        }
    }
    if (lane == 63) { tAr[w] = Ar; tAi[w] = Ai; tSr[w] = Sr; tSi[w] = Si; tC[w] = C; }
    __syncthreads();

    // level 2: serial exclusive scan over 8 wave totals (thread 0)
    if (i == 0) {
        double rAr = 1., rAi = 0., rSr = 0., rSi = 0.; float rC = 0.f;
        for (int k = 0; k < 8; ++k) {
            eAr[k] = rAr; eAi[k] = rAi; eSr[k] = rSr; eSi[k] = rSi; eC[k] = rC;
            double gAr = tAr[k], gAi = tAi[k], gSr = tSr[k], gSi = tSi[k];
            float gC = tC[k];
            if (gC != 0.f) { rAr = gAr; rAi = gAi; rSr = gSr; rSi = gSi; rC = gC; }
            else {
                double nAr = gAr * rAr - gAi * rAi;
                double nAi = gAr * rAi + gAi * rAr;
                double nSr = gAr * rSr - gAi * rSi + gSr;
                double nSi = gAr * rSi + gAi * rSr + gSi;
                rAr = nAr; rAi = nAi; rSr = nSr; rSi = nSi;   // rC unchanged
            }
        }
    }
    __syncthreads();

    // level 3: full prefix of chunk i-1 (exclusive), then apply carry
    double pAr = __shfl_up(Ar, 1), pAi = __shfl_up(Ai, 1);
    double pSr = __shfl_up(Sr, 1), pSi = __shfl_up(Si, 1);
    float  pC  = __shfl_up(C, 1);
    double fAr, fAi, fSr, fSi; float fC;
    if (lane == 0) {
        fAr = eAr[w]; fAi = eAi[w]; fSr = eSr[w]; fSi = eSi[w]; fC = eC[w];
    } else if (pC != 0.f) {
        fAr = pAr; fAi = pAi; fSr = pSr; fSi = pSi; fC = pC;
    } else {
        fAr = pAr * eAr[w] - pAi * eAi[w];
        fAi = pAr * eAi[w] + pAi * eAr[w];
        fSr = pAr * eSr[w] - pAi * eSi[w] + pSr;
        fSi = pAr * eSi[w] + pAi * eSr[w] + pSi;
        fC = eC[w];
    }
    double c0r = (double)carry[2 * p], c0i = (double)carry[2 * p + 1];
    double pr, pi_;
    if (fC != 0.f) { pr = fSr; pi_ = fSi; }
    else {
        pr  = fAr * c0r - fAi * c0i + fSr;
        pi_ = fAr * c0i + fAi * c0r + fSi;
    }
    prefix[(size_t)i * 1024 + 2 * p]     = pr;
    prefix[(size_t)i * 1024 + 2 * p + 1] = pi_;
}

// ---------------------------------------------------------------------------
// Scan phase C (f64): re-scan each chunk (CS=16) from its prefix; write
// states as bf16 hi/lo in place. lambda_bar inline. Last chunk -> carry out.
// ---------------------------------------------------------------------------
__global__ __launch_bounds__(512) void scanC_kernel(
    unsigned short* __restrict__ Shi, unsigned short* __restrict__ Slo,
    const float* __restrict__ mask,
    const float* __restrict__ lam_re, const float* __restrict__ lam_im,
    const float* __restrict__ log_step,
    const double* __restrict__ prefix,
    float* __restrict__ carry_out, int carry_elems) {
    int p = threadIdx.x;
    int blk = blockIdx.x;
    double lbr, lbi;
    lbar_of(lam_re, lam_im, log_step, p, lbr, lbi);
    double sr = prefix[(size_t)blk * 1024 + 2 * p];
    double si = prefix[(size_t)blk * 1024 + 2 * p + 1];
    ushort2* H2 = (ushort2*)Shi;
    ushort2* L2 = (ushort2*)Slo;
    int t0 = blk * CS;
    for (int t = t0; t < t0 + CS; ++t) {
        float m = mask[t];
        ushort2 h2 = H2[(size_t)t * P_DIM + p];
        ushort2 l2 = L2[(size_t)t * P_DIM + p];
        double bxr = (double)(bf2f(h2.x) + bf2f(l2.x));
        double bxi = (double)(bf2f(h2.y) + bf2f(l2.y));
        if (m != 0.f) {
            sr = bxr; si = bxi;
        } else {
            double nr = lbr * sr - lbi * si + bxr;
            si = lbr * si + lbi * sr + bxi;
            sr = nr;
        }
        float sf = (float)sr, sif = (float)si;
        ushort2 ho, lo;
        ho.x = f2bf(sf);  lo.x = f2bf(sf - bf2f(ho.x));
        ho.y = f2bf(sif); lo.y = f2bf(sif - bf2f(ho.y));
        H2[(size_t)t * P_DIM + p] = ho;
        L2[(size_t)t * P_DIM + p] = lo;
    }
    if (blk == NB - 1) {
        if (carry_elems >= 1024) {
            carry_out[2 * p] = (float)sr;
            carry_out[2 * p + 1] = (float)si;
        } else {
            carry_out[p] = (float)sr;   // real part only
        }
    }
}

// ---------------------------------------------------------------------------
extern "C" void kernel_launch(void* const* d_in, const int* in_sizes, int n_in,
                              void* d_out, int out_size, void* d_ws, size_t ws_size,
                              hipStream_t stream) {
    const float* x           = (const float*)d_in[0];  // T*H
    const float* mask        = (const float*)d_in[1];  // T
    const float* carry       = (const float*)d_in[2];  // 1*P*2
    const float* lambda_real = (const float*)d_in[3];  // P
    const float* lambda_imag = (const float*)d_in[4];  // P
    const float* b           = (const float*)d_in[5];  // P*H*2
    const float* c           = (const float*)d_in[6];  // H*P*2
    const float* d           = (const float*)d_in[7];  // H
    const float* log_step    = (const float*)d_in[8];  // P*1

    float* out = (float*)d_out;
    char* ws = (char*)d_ws;

    int carry_elems = out_size - T_LEN * H_DIM;
    if (carry_elems != 512 && carry_elems != 1024) carry_elems = 1024;
    float* ys_out = out + carry_elems;

    // workspace layout: 8B-aligned first, then 4B, then 2B
    double* cA     = (double*)ws;                        ws += (size_t)NB * 1024 * 8;
    double* cSb    = (double*)ws;                        ws += (size_t)NB * 1024 * 8;
    double* prefix = (double*)ws;                        ws += (size_t)NB * 1024 * 8;
    float* cC      = (float*)ws;                         ws += (size_t)NB * P_DIM * 4;
    unsigned short* xhi   = (unsigned short*)ws;         ws += (size_t)T_LEN * H_DIM * 2;
    unsigned short* xlo   = (unsigned short*)ws;         ws += (size_t)T_LEN * H_DIM * 2;
    unsigned short* Bt1hi = (unsigned short*)ws;         ws += (size_t)(2 * P_DIM) * H_DIM * 2;
    unsigned short* Bt1lo = (unsigned short*)ws;         ws += (size_t)(2 * P_DIM) * H_DIM * 2;
    unsigned short* Bt2hi = (unsigned short*)ws;         ws += (size_t)H_DIM * (2 * P_DIM) * 2;
    unsigned short* Bt2lo = (unsigned short*)ws;         ws += (size_t)H_DIM * (2 * P_DIM) * 2;
    unsigned short* Shi   = (unsigned short*)ws;         ws += (size_t)T_LEN * (2 * P_DIM) * 2;
    unsigned short* Slo   = (unsigned short*)ws;         ws += (size_t)T_LEN * (2 * P_DIM) * 2;

    // 1) prep (x split + B fills; coef inline)
    prep_kernel<<<(T_LEN * H_DIM / 4) / 256, 256, 0, stream>>>(
        x, b, c, lambda_real, lambda_imag, log_step,
        xhi, xlo, Bt1hi, Bt1lo, Bt2hi, Bt2lo);

    // 2) GEMM1 + fused scanA: S = x @ bbar^T (bf16 hi/lo) + chunk summaries
    {
        dim3 grid((2 * P_DIM) / 128, T_LEN / 128);   // (8, 64)
        gemm_mfma_split<0><<<grid, 512, 0, stream>>>(
            xhi, xlo, H_DIM, Bt1hi, Bt1lo, H_DIM,
            Shi, Slo, 2 * P_DIM, H_DIM, nullptr, nullptr,
            mask, lambda_real, lambda_imag, log_step, cA, cSb, cC);
    }

    // 3) chunk-prefix scan (B) + re-scan (C), f64 state arithmetic
    scanB_kernel<<<P_DIM, NB, 0, stream>>>(cA, cSb, cC, carry, prefix);
    scanC_kernel<<<NB, 512, 0, stream>>>(Shi, Slo, mask,
                                         lambda_real, lambda_imag, log_step,
                                         prefix, out, carry_elems);

    // 4) GEMM2 (MFMA split-bf16): ys[T x H] = S @ B2 + d*x -> f32
    {
        dim3 grid(H_DIM / 128, T_LEN / 128);         // (4, 64)
        gemm_mfma_split<1><<<grid, 512, 0, stream>>>(
            Shi, Slo, 2 * P_DIM, Bt2hi, Bt2lo, 2 * P_DIM,
            ys_out, nullptr, H_DIM, 2 * P_DIM, d, x,
            nullptr, nullptr, nullptr, nullptr, nullptr, nullptr, nullptr);
    }
}

// Round 13
// 107.694 us; speedup vs baseline: 1.0288x; 1.0288x over previous
//
#include <hip/hip_runtime.h>
#include <hip/hip_bf16.h>

#define T_LEN 8192
#define H_DIM 512
#define P_DIM 512
#define CS 16
#define NB (T_LEN / CS)   // 512 chunks

typedef __attribute__((ext_vector_type(8))) __bf16 bf16x8;
typedef __attribute__((ext_vector_type(4))) float f32x4;

__device__ __forceinline__ unsigned short f2bf(float f) {
    __bf16 h = (__bf16)f;
    return __builtin_bit_cast(unsigned short, h);
}
__device__ __forceinline__ float bf2f(unsigned short u) {
    unsigned v = ((unsigned)u) << 16;
    return __builtin_bit_cast(float, v);
}

__device__ __forceinline__ void gload_lds16(void* g, void* l) {
    __builtin_amdgcn_global_load_lds(
        (__attribute__((address_space(1))) unsigned*)g,
        (__attribute__((address_space(3))) unsigned*)l, 16, 0, 0);
}

// lambda_bar(p) in f64 — formula identical everywhere it is inlined.
__device__ __forceinline__ void lbar_of(const float* lam_re, const float* lam_im,
                                        const float* log_step, int p,
                                        double& lbr, double& lbi) {
    double lr = fmin((double)lam_re[p], -1e-4);
    double li = (double)lam_im[p];
    double step = exp((double)log_step[p]);          // STEP_RESCALE = 1
    double er = exp(lr * step);
    double ang = li * step;
    lbr = er * cos(ang);
    lbi = er * sin(ang);
}

// ---------------------------------------------------------------------------
// prep: 4096 blocks: x (f32) -> xhi/xlo bf16 split, float4 in / 8B out.
//       blocks < 1024 additionally fill Bt1 / Bt2 as bf16 hi/lo; coef inline.
// ---------------------------------------------------------------------------
__global__ __launch_bounds__(256) void prep_kernel(
    const float* __restrict__ x,
    const float* __restrict__ b, const float* __restrict__ c,
    const float* __restrict__ lam_re, const float* __restrict__ lam_im,
    const float* __restrict__ log_step,
    unsigned short* __restrict__ xhi, unsigned short* __restrict__ xlo,
    unsigned short* __restrict__ Bt1hi, unsigned short* __restrict__ Bt1lo,
    unsigned short* __restrict__ Bt2hi, unsigned short* __restrict__ Bt2lo) {
    int idx = blockIdx.x * 256 + threadIdx.x;        // 0 .. T*H/4-1
    {
        float4 v = ((const float4*)x)[idx];
        ushort4 h, l;
        h.x = f2bf(v.x); l.x = f2bf(v.x - bf2f(h.x));
        h.y = f2bf(v.y); l.y = f2bf(v.y - bf2f(h.y));
        h.z = f2bf(v.z); l.z = f2bf(v.z - bf2f(h.z));
        h.w = f2bf(v.w); l.w = f2bf(v.w - bf2f(h.w));
        ((ushort4*)xhi)[idx] = h;
        ((ushort4*)xlo)[idx] = l;
    }
    if (blockIdx.x < (P_DIM * H_DIM) / 256) {
        int idx2 = blockIdx.x * 256 + threadIdx.x;   // 0 .. 262143
        {   // Bt1: rows 2p,2p+1 (stride H_DIM), coalesced in h
            int p = idx2 >> 9, h = idx2 & 511;
            double lr = fmin((double)lam_re[p], -1e-4);
            double li = (double)lam_im[p];
            double step = exp((double)log_step[p]);
            double er = exp(lr * step);
            double ang = li * step;
            double lbr = er * cos(ang), lbi = er * sin(ang);
            double nr = lbr - 1.0, ni = lbi;
            double den = lr * lr + li * li;
            double cr = (nr * lr + ni * li) / den;
            double ci = (ni * lr - nr * li) / den;
            float2 bv = ((const float2*)b)[(size_t)p * H_DIM + h];
            float re = (float)(cr * (double)bv.x - ci * (double)bv.y);
            float im = (float)(cr * (double)bv.y + ci * (double)bv.x);
            unsigned short rh = f2bf(re), ih = f2bf(im);
            Bt1hi[(size_t)(2 * p) * H_DIM + h]     = rh;
            Bt1lo[(size_t)(2 * p) * H_DIM + h]     = f2bf(re - bf2f(rh));
            Bt1hi[(size_t)(2 * p + 1) * H_DIM + h] = ih;
            Bt1lo[(size_t)(2 * p + 1) * H_DIM + h] = f2bf(im - bf2f(ih));
        }
        {   // Bt2: row h (stride 2P), cols 2p,2p+1 -> ushort2, coalesced in p
            int h = idx2 >> 9, p = idx2 & 511;
            float2 cv = ((const float2*)c)[(size_t)h * P_DIM + p];
            float re = cv.x, im = -cv.y;
            ushort2 hi, lo;
            hi.x = f2bf(re); lo.x = f2bf(re - bf2f(hi.x));
            hi.y = f2bf(im); lo.y = f2bf(im - bf2f(hi.y));
            ((ushort2*)Bt2hi)[(size_t)h * P_DIM + p] = hi;
            ((ushort2*)Bt2lo)[(size_t)h * P_DIM + p] = lo;
        }
    }
}

// ---------------------------------------------------------------------------
// Split-bf16 MFMA GEMM (R11 known-good): C = (Ahi+Alo) * (Bthi+Btlo)^T.
// 128x128 tile, BK=32, 256 thr = 4 waves (2x2); wave tile 64x64, acc 4x4.
// 3 MFMA passes (hh, hl, lh), fp32 accumulate.
// MODE 0: write C as bf16 hi/lo split + fused scanA chunk summaries.
// MODE 1: write f32 C + D[col]*X[row][col].
// LDS tiles [128 rows][32 shorts=64B], chunk-swizzled: pos = c ^ ((row>>1)&3).
// XCD-aware block swizzle (bijective; gridDim.y % 8 == 0).
// ---------------------------------------------------------------------------
template <int MODE>
__global__ __launch_bounds__(256) void gemm_mfma_split(
    const unsigned short* __restrict__ Ahi, const unsigned short* __restrict__ Alo,
    int lda,
    const unsigned short* __restrict__ Bthi, const unsigned short* __restrict__ Btlo,
    int ldb,
    void* __restrict__ Cout0, void* __restrict__ Cout1, int ldc, int K,
    const float* __restrict__ Dvec, const float* __restrict__ X,
    const float* __restrict__ mask,
    const float* __restrict__ lam_re, const float* __restrict__ lam_im,
    const float* __restrict__ log_step,
    double* __restrict__ cA, double* __restrict__ cS, float* __restrict__ cC) {
    __shared__ __align__(16) unsigned short lds[2][4][128 * 32];
    const int tid = threadIdx.x;
    const int lane = tid & 63, wid = tid >> 6;
    const int wm = wid >> 1, wn = wid & 1;

    // XCD swizzle (bijective: gy % 8 == 0)
    const int id = blockIdx.y * gridDim.x + blockIdx.x;
    const int nx = gridDim.x, rpx = gridDim.y >> 3;
    const int xcd = id & 7, j = id >> 3;
    const int by = xcd * rpx + j / nx;
    const int bx = j % nx;
    const int bm = by * 128, bn = bx * 128;

    // staging source for this wave: tile wid of {Ahi, Alo, Bthi, Btlo}
    const unsigned short* ssrc;
    int srow0, sld;
    if (wid == 0)      { ssrc = Ahi;  srow0 = bm; sld = lda; }
    else if (wid == 1) { ssrc = Alo;  srow0 = bm; sld = lda; }
    else if (wid == 2) { ssrc = Bthi; srow0 = bn; sld = ldb; }
    else               { ssrc = Btlo; srow0 = bn; sld = ldb; }

    f32x4 acc[4][4];
#pragma unroll
    for (int i = 0; i < 4; ++i)
#pragma unroll
        for (int j2 = 0; j2 < 4; ++j2) acc[i][j2] = (f32x4)(0.0f);

    // stage one [128][32] bf16 tile (8 KB) = 8 x 1024B instructions
    auto stage = [&](int buf, int k0) {
        unsigned short* base = &lds[buf][wid][0];
#pragma unroll
        for (int s = 0; s < 8; ++s) {
            int r = s * 16 + (lane >> 2);
            int cg = (lane & 3) ^ ((r >> 1) & 3);
            void* g = (void*)((const char*)(ssrc + (size_t)(srow0 + r) * sld + k0)
                              + cg * 16);
            gload_lds16(g, (void*)((char*)base + s * 1024));
        }
    };

    stage(0, 0);
    __syncthreads();   // drains vmcnt

    const int nk = K / 32;
    for (int t = 0; t < nk; ++t) {
        int cur = t & 1;
        if (t + 1 < nk) stage(cur ^ 1, (t + 1) * 32);

        bf16x8 ah[4], al[4], bh[4], bl[4];
#pragma unroll
        for (int i = 0; i < 4; ++i) {
            int rA = wm * 64 + i * 16 + (lane & 15);
            int byA = rA * 64 + ((((lane >> 4)) ^ ((rA >> 1) & 3)) << 4);
            ah[i] = *(const bf16x8*)((const char*)&lds[cur][0][0] + byA);
            al[i] = *(const bf16x8*)((const char*)&lds[cur][1][0] + byA);
            int rB = wn * 64 + i * 16 + (lane & 15);
            int byB = rB * 64 + ((((lane >> 4)) ^ ((rB >> 1) & 3)) << 4);
            bh[i] = *(const bf16x8*)((const char*)&lds[cur][2][0] + byB);
            bl[i] = *(const bf16x8*)((const char*)&lds[cur][3][0] + byB);
        }
#pragma unroll
        for (int i = 0; i < 4; ++i)
#pragma unroll
            for (int j2 = 0; j2 < 4; ++j2) {
                acc[i][j2] = __builtin_amdgcn_mfma_f32_16x16x32_bf16(
                    ah[i], bh[j2], acc[i][j2], 0, 0, 0);
                acc[i][j2] = __builtin_amdgcn_mfma_f32_16x16x32_bf16(
                    ah[i], bl[j2], acc[i][j2], 0, 0, 0);
                acc[i][j2] = __builtin_amdgcn_mfma_f32_16x16x32_bf16(
                    al[i], bh[j2], acc[i][j2], 0, 0, 0);
            }
        __syncthreads();
    }

    // epilogue. C/D map (verified m89/m91): col = lane&15, row = 4*(lane>>4)+reg
#pragma unroll
    for (int i = 0; i < 4; ++i)
#pragma unroll
        for (int j2 = 0; j2 < 4; ++j2) {
            int col = bn + wn * 64 + j2 * 16 + (lane & 15);
#pragma unroll
            for (int r = 0; r < 4; ++r) {
                int row = bm + wm * 64 + i * 16 + (lane >> 4) * 4 + r;
                float v = acc[i][j2][r];
                if (MODE == 0) {
                    unsigned short h = f2bf(v);
                    unsigned short lo = f2bf(v - bf2f(h));
                    ((unsigned short*)Cout0)[(size_t)row * ldc + col] = h;
                    ((unsigned short*)Cout1)[(size_t)row * ldc + col] = lo;
                } else {
                    v += Dvec[col] * X[(size_t)row * ldc + col];
                    ((float*)Cout0)[(size_t)row * ldc + col] = v;
                }
            }
        }

    // ---- fused scanA (MODE 0 only): per-chunk fold of this block's tile ----
    if constexpr (MODE == 0) {
        float* fl = (float*)&lds[0][0][0];   // reuse staging LDS: [128][128] f32
#pragma unroll
        for (int i = 0; i < 4; ++i)
#pragma unroll
            for (int j2 = 0; j2 < 4; ++j2) {
                int lcol = wn * 64 + j2 * 16 + (lane & 15);
#pragma unroll
                for (int r = 0; r < 4; ++r) {
                    int lrow = wm * 64 + i * 16 + (lane >> 4) * 4 + r;
                    fl[lrow * 128 + lcol] = acc[i][j2][r];
                }
            }
        __syncthreads();
        const int NCH = 128 / CS;            // 8 chunks per block
        int q = tid & 63;                    // local p (same for both w-iters)
        int pg = (bn >> 1) + q;              // global p
        double lbr, lbi;
        lbar_of(lam_re, lam_im, log_step, pg, lbr, lbi);
        for (int w = tid; w < 64 * NCH; w += 256) {
            int ck = w >> 6;                 // local chunk
            double Ar = 1., Ai = 0., Sr = 0., Si = 0.;
            float Cc = 0.f;
            for (int k = 0; k < CS; ++k) {
                int row = ck * CS + k;
                float m = mask[bm + row];
                double bxr = (double)fl[row * 128 + 2 * q];
                double bxi = (double)fl[row * 128 + 2 * q + 1];
                if (m != 0.f) {
                    Ar = lbr; Ai = lbi; Sr = bxr; Si = bxi; Cc = 1.f;
                } else {
                    double nAr = lbr * Ar - lbi * Ai;
                    Ai = lbr * Ai + lbi * Ar; Ar = nAr;
                    double nSr = lbr * Sr - lbi * Si + bxr;
                    Si = lbr * Si + lbi * Sr + bxi; Sr = nSr;
                }
            }
            int cg = (bm / CS) + ck;         // global chunk
            cA[(size_t)cg * 1024 + 2 * pg]     = Ar;
            cA[(size_t)cg * 1024 + 2 * pg + 1] = Ai;
            cS[(size_t)cg * 1024 + 2 * pg]     = Sr;
            cS[(size_t)cg * 1024 + 2 * pg + 1] = Si;
            cC[(size_t)cg * P_DIM + pg] = Cc;
        }
    }
}

// ---------------------------------------------------------------------------
// Scan phase B (f64, parallel, shuffle-based): one block per p (512 blocks),
// NB=512 threads (one per chunk) = 8 waves. In-wave Kogge-Stone via
// __shfl_up, serial scan of 8 wave totals, apply wave prefix + carry.
// ---------------------------------------------------------------------------
__global__ __launch_bounds__(NB) void scanB_kernel(
    const double* __restrict__ cA, const double* __restrict__ cS,
    const float* __restrict__ cC, const float* __restrict__ carry,
    double* __restrict__ prefix) {
    int p = blockIdx.x;      // 0..511
    int i = threadIdx.x;     // chunk 0..NB-1
    int lane = i & 63, w = i >> 6;
    __shared__ double tAr[8], tAi[8], tSr[8], tSi[8];
    __shared__ float  tC[8];
    __shared__ double eAr[8], eAi[8], eSr[8], eSi[8];
    __shared__ float  eC[8];

    double Ar = cA[(size_t)i * 1024 + 2 * p];
    double Ai = cA[(size_t)i * 1024 + 2 * p + 1];
    double Sr = cS[(size_t)i * 1024 + 2 * p];
    double Si = cS[(size_t)i * 1024 + 2 * p + 1];
    float  C  = cC[(size_t)i * P_DIM + p];

    // level 1: in-wave inclusive Kogge-Stone
#pragma unroll
    for (int d = 1; d < 64; d <<= 1) {
        double pAr = __shfl_up(Ar, d), pAi = __shfl_up(Ai, d);
        double pSr = __shfl_up(Sr, d), pSi = __shfl_up(Si, d);
        float  pC  = __shfl_up(C, d);
        if (lane >= d && C == 0.f) {
            double nAr = Ar * pAr - Ai * pAi;
            double nAi = Ar * pAi + Ai * pAr;
            double nSr = Ar * pSr - Ai * pSi + Sr;
            double nSi = Ar * pSi + Ai * pSr + Si;
            Ar = nAr; Ai = nAi; Sr = nSr; Si = nSi; C = pC;
        }
    }
    if (lane == 63) { tAr[w] = Ar; tAi[w] = Ai; tSr[w] = Sr; tSi[w] = Si; tC[w] = C; }
    __syncthreads();

    // level 2: serial exclusive scan over 8 wave totals (thread 0)
    if (i == 0) {
        double rAr = 1., rAi = 0., rSr = 0., rSi = 0.; float rC = 0.f;
        for (int k = 0; k < 8; ++k) {
            eAr[k] = rAr; eAi[k] = rAi; eSr[k] = rSr; eSi[k] = rSi; eC[k] = rC;
            double gAr = tAr[k], gAi = tAi[k], gSr = tSr[k], gSi = tSi[k];
            float gC = tC[k];
            if (gC != 0.f) { rAr = gAr; rAi = gAi; rSr = gSr; rSi = gSi; rC = gC; }
            else {
                double nAr = gAr * rAr - gAi * rAi;
                double nAi = gAr * rAi + gAi * rAr;
                double nSr = gAr * rSr - gAi * rSi + gSr;
                double nSi = gAr * rSi + gAi * rSr + gSi;
                rAr = nAr; rAi = nAi; rSr = nSr; rSi = nSi;   // rC unchanged
            }
        }
    }
    __syncthreads();

    // level 3: full prefix of chunk i-1 (exclusive), then apply carry
    double pAr = __shfl_up(Ar, 1), pAi = __shfl_up(Ai, 1);
    double pSr = __shfl_up(Sr, 1), pSi = __shfl_up(Si, 1);
    float  pC  = __shfl_up(C, 1);
    double fAr, fAi, fSr, fSi; float fC;
    if (lane == 0) {
        fAr = eAr[w]; fAi = eAi[w]; fSr = eSr[w]; fSi = eSi[w]; fC = eC[w];
    } else if (pC != 0.f) {
        fAr = pAr; fAi = pAi; fSr = pSr; fSi = pSi; fC = pC;
    } else {
        fAr = pAr * eAr[w] - pAi * eAi[w];
        fAi = pAr * eAi[w] + pAi * eAr[w];
        fSr = pAr * eSr[w] - pAi * eSi[w] + pSr;
        fSi = pAr * eSi[w] + pAi * eSr[w] + pSi;
        fC = eC[w];
    }
    double c0r = (double)carry[2 * p], c0i = (double)carry[2 * p + 1];
    double pr, pi_;
    if (fC != 0.f) { pr = fSr; pi_ = fSi; }
    else {
        pr  = fAr * c0r - fAi * c0i + fSr;
        pi_ = fAr * c0i + fAi * c0r + fSi;
    }
    prefix[(size_t)i * 1024 + 2 * p]     = pr;
    prefix[(size_t)i * 1024 + 2 * p + 1] = pi_;
}

// ---------------------------------------------------------------------------
// Scan phase C (f64): re-scan each chunk (CS=16) from its prefix; write
// states as bf16 hi/lo in place. lambda_bar inline. Last chunk -> carry out.
// ---------------------------------------------------------------------------
__global__ __launch_bounds__(512) void scanC_kernel(
    unsigned short* __restrict__ Shi, unsigned short* __restrict__ Slo,
    const float* __restrict__ mask,
    const float* __restrict__ lam_re, const float* __restrict__ lam_im,
    const float* __restrict__ log_step,
    const double* __restrict__ prefix,
    float* __restrict__ carry_out, int carry_elems) {
    int p = threadIdx.x;
    int blk = blockIdx.x;
    double lbr, lbi;
    lbar_of(lam_re, lam_im, log_step, p, lbr, lbi);
    double sr = prefix[(size_t)blk * 1024 + 2 * p];
    double si = prefix[(size_t)blk * 1024 + 2 * p + 1];
    ushort2* H2 = (ushort2*)Shi;
    ushort2* L2 = (ushort2*)Slo;
    int t0 = blk * CS;
    for (int t = t0; t < t0 + CS; ++t) {
        float m = mask[t];
        ushort2 h2 = H2[(size_t)t * P_DIM + p];
        ushort2 l2 = L2[(size_t)t * P_DIM + p];
        double bxr = (double)(bf2f(h2.x) + bf2f(l2.x));
        double bxi = (double)(bf2f(h2.y) + bf2f(l2.y));
        if (m != 0.f) {
            sr = bxr; si = bxi;
        } else {
            double nr = lbr * sr - lbi * si + bxr;
            si = lbr * si + lbi * sr + bxi;
            sr = nr;
        }
        float sf = (float)sr, sif = (float)si;
        ushort2 ho, lo;
        ho.x = f2bf(sf);  lo.x = f2bf(sf - bf2f(ho.x));
        ho.y = f2bf(sif); lo.y = f2bf(sif - bf2f(ho.y));
        H2[(size_t)t * P_DIM + p] = ho;
        L2[(size_t)t * P_DIM + p] = lo;
    }
    if (blk == NB - 1) {
        if (carry_elems >= 1024) {
            carry_out[2 * p] = (float)sr;
            carry_out[2 * p + 1] = (float)si;
        } else {
            carry_out[p] = (float)sr;   // real part only
        }
    }
}

// ---------------------------------------------------------------------------
extern "C" void kernel_launch(void* const* d_in, const int* in_sizes, int n_in,
                              void* d_out, int out_size, void* d_ws, size_t ws_size,
                              hipStream_t stream) {
    const float* x           = (const float*)d_in[0];  // T*H
    const float* mask        = (const float*)d_in[1];  // T
    const float* carry       = (const float*)d_in[2];  // 1*P*2
    const float* lambda_real = (const float*)d_in[3];  // P
    const float* lambda_imag = (const float*)d_in[4];  // P
    const float* b           = (const float*)d_in[5];  // P*H*2
    const float* c           = (const float*)d_in[6];  // H*P*2
    const float* d           = (const float*)d_in[7];  // H
    const float* log_step    = (const float*)d_in[8];  // P*1

    float* out = (float*)d_out;
    char* ws = (char*)d_ws;

    int carry_elems = out_size - T_LEN * H_DIM;
    if (carry_elems != 512 && carry_elems != 1024) carry_elems = 1024;
    float* ys_out = out + carry_elems;

    // workspace layout: 8B-aligned first, then 4B, then 2B
    double* cA     = (double*)ws;                        ws += (size_t)NB * 1024 * 8;
    double* cSb    = (double*)ws;                        ws += (size_t)NB * 1024 * 8;
    double* prefix = (double*)ws;                        ws += (size_t)NB * 1024 * 8;
    float* cC      = (float*)ws;                         ws += (size_t)NB * P_DIM * 4;
    unsigned short* xhi   = (unsigned short*)ws;         ws += (size_t)T_LEN * H_DIM * 2;
    unsigned short* xlo   = (unsigned short*)ws;         ws += (size_t)T_LEN * H_DIM * 2;
    unsigned short* Bt1hi = (unsigned short*)ws;         ws += (size_t)(2 * P_DIM) * H_DIM * 2;
    unsigned short* Bt1lo = (unsigned short*)ws;         ws += (size_t)(2 * P_DIM) * H_DIM * 2;
    unsigned short* Bt2hi = (unsigned short*)ws;         ws += (size_t)H_DIM * (2 * P_DIM) * 2;
    unsigned short* Bt2lo = (unsigned short*)ws;         ws += (size_t)H_DIM * (2 * P_DIM) * 2;
    unsigned short* Shi   = (unsigned short*)ws;         ws += (size_t)T_LEN * (2 * P_DIM) * 2;
    unsigned short* Slo   = (unsigned short*)ws;         ws += (size_t)T_LEN * (2 * P_DIM) * 2;

    // 1) prep (x split + B fills; coef inline)
    prep_kernel<<<(T_LEN * H_DIM / 4) / 256, 256, 0, stream>>>(
        x, b, c, lambda_real, lambda_imag, log_step,
        xhi, xlo, Bt1hi, Bt1lo, Bt2hi, Bt2lo);

    // 2) GEMM1 + fused scanA: S = x @ bbar^T (bf16 hi/lo) + chunk summaries
    {
        dim3 grid((2 * P_DIM) / 128, T_LEN / 128);   // (8, 64)
        gemm_mfma_split<0><<<grid, 256, 0, stream>>>(
            xhi, xlo, H_DIM, Bt1hi, Bt1lo, H_DIM,
            Shi, Slo, 2 * P_DIM, H_DIM, nullptr, nullptr,
            mask, lambda_real, lambda_imag, log_step, cA, cSb, cC);
    }

    // 3) chunk-prefix scan (B) + re-scan (C), f64 state arithmetic
    scanB_kernel<<<P_DIM, NB, 0, stream>>>(cA, cSb, cC, carry, prefix);
    scanC_kernel<<<NB, 512, 0, stream>>>(Shi, Slo, mask,
                                         lambda_real, lambda_imag, log_step,
                                         prefix, out, carry_elems);

    // 4) GEMM2 (MFMA split-bf16): ys[T x H] = S @ B2 + d*x -> f32
    {
        dim3 grid(H_DIM / 128, T_LEN / 128);         // (4, 64)
        gemm_mfma_split<1><<<grid, 256, 0, stream>>>(
            Shi, Slo, 2 * P_DIM, Bt2hi, Bt2lo, 2 * P_DIM,
            ys_out, nullptr, H_DIM, 2 * P_DIM, d, x,
            nullptr, nullptr, nullptr, nullptr, nullptr, nullptr, nullptr);
    }
}